// Round 3
// baseline (1037.381 us; speedup 1.0000x reference)
//
#include <hip/hip_runtime.h>

// GAT (2-layer) + global mean pool + linear, MI355X.
// R1: gemm_alpha restructured — coalesced 8-row staging into wave-private LDS,
// W-broadcast compute (was: lane-uniform serialized global loads, 147us/dispatch).
// R2: resubmission of R1 (broker timeout — never benched).

constexpr int FH = 64;        // hidden/out feature width (both layers)
constexpr float NEG_SLOPE = 0.2f;
constexpr float EPS = 1e-16f;

// ---------------- CSR build ----------------

__global__ void hist_kernel(const int* __restrict__ ei, int* __restrict__ deg,
                            int E, int N) {
  int e = blockIdx.x * blockDim.x + threadIdx.x;
  if (e >= E + N) return;
  int dst = (e < E) ? ei[E + e] : (e - E);   // self-loops appended
  atomicAdd(&deg[dst], 1);
}

// single-block exclusive scan (n up to ~64k: 1024 threads, chunked)
__global__ void scan_kernel(const int* __restrict__ deg, int* __restrict__ rowptr,
                            int n) {
  __shared__ int buf[1024];
  __shared__ int carry;
  int t = threadIdx.x;
  if (t == 0) carry = 0;
  __syncthreads();
  for (int base = 0; base < n; base += 1024) {
    int i = base + t;
    int v = (i < n) ? deg[i] : 0;
    buf[t] = v;
    __syncthreads();
    for (int off = 1; off < 1024; off <<= 1) {
      int add = (t >= off) ? buf[t - off] : 0;
      __syncthreads();
      buf[t] += add;
      __syncthreads();
    }
    if (i < n) rowptr[i] = carry + buf[t] - v;   // exclusive
    __syncthreads();
    if (t == 0) carry += buf[1023];
    __syncthreads();
  }
  if (t == 0) rowptr[n] = carry;
}

__global__ void scatter_kernel(const int* __restrict__ ei, int* __restrict__ cursor,
                               int* __restrict__ eidx, int E, int N) {
  int e = blockIdx.x * blockDim.x + threadIdx.x;
  if (e >= E + N) return;
  int src, dst;
  if (e < E) { src = ei[e]; dst = ei[E + e]; }
  else       { src = dst = e - E; }
  int pos = atomicAdd(&cursor[dst], 1);
  eidx[pos] = src;
}

// ---------------- h = x @ W, plus alpha_s/alpha_d dot products ----------------
// Block = 256 threads = 4 waves. W staged in LDS once per block.
// Each wave owns 8 rows per group: lanes load the 8xFIN block COALESCED into a
// wave-private LDS buffer (no barrier: wave-synchronous), then compute with
// W[k][lane] LDS reads (2-way, free) amortized over 8 rows of broadcast x reads.

template <int FIN>
__global__ void __launch_bounds__(256) gemm_alpha_kernel(
    const float* __restrict__ x, const float* __restrict__ W,
    const float* __restrict__ avs, const float* __restrict__ avd,
    float* __restrict__ h, float* __restrict__ as, float* __restrict__ ad,
    int n) {
  constexpr int K4 = FIN / 4;
  __shared__ float Wl[FIN][FH];              // 64 cols, row-major
  __shared__ float4 xbuf[4][8 * K4];         // per-wave [8 rows][FIN] as float4
  for (int i = threadIdx.x; i < FIN * FH; i += 256)
    Wl[i >> 6][i & 63] = W[i];
  __syncthreads();

  int wave = threadIdx.x >> 6;
  int lane = threadIdx.x & 63;
  float asc = avs[lane];
  float adc = avd[lane];
  float4* xb = xbuf[wave];
  int nw = gridDim.x * 4;
  int ngroups = n >> 3;                      // n = 50000 = 8*6250
  for (int g = blockIdx.x * 4 + wave; g < ngroups; g += nw) {
    int r0 = g << 3;
    const float4* xg = reinterpret_cast<const float4*>(x + (size_t)r0 * FIN);
    // coalesced stage: 8*K4 float4s, lane-strided
#pragma unroll
    for (int f = lane; f < 8 * K4; f += 64) xb[f] = xg[f];
    // wave-synchronous LDS RAW (compiler inserts lgkmcnt wait); no barrier
    float acc[8];
#pragma unroll
    for (int r = 0; r < 8; ++r) acc[r] = 0.f;
#pragma unroll
    for (int k4 = 0; k4 < K4; ++k4) {
      int k = k4 * 4;
      float w0 = Wl[k + 0][lane];
      float w1 = Wl[k + 1][lane];
      float w2 = Wl[k + 2][lane];
      float w3 = Wl[k + 3][lane];
#pragma unroll
      for (int r = 0; r < 8; ++r) {
        float4 xv = xb[r * K4 + k4];         // broadcast read, conflict-free
        acc[r] += xv.x * w0 + xv.y * w1 + xv.z * w2 + xv.w * w3;
      }
    }
#pragma unroll
    for (int r = 0; r < 8; ++r) {
      h[(size_t)(r0 + r) * FH + lane] = acc[r];
      float s = acc[r] * asc, d = acc[r] * adc;
#pragma unroll
      for (int off = 32; off; off >>= 1) {
        s += __shfl_xor(s, off);
        d += __shfl_xor(d, off);
      }
      if (lane == 0) { as[r0 + r] = s; ad[r0 + r] = d; }
    }
  }
}

// ---------------- per-dst softmax aggregation (gather) ----------------
// One wave per dst. Pass 1: lanes stride edges, reduce max(logit).
// Pass 2: serial edge loop; lane c owns feature c; denom redundant per lane.

__global__ void agg_kernel(const int* __restrict__ rowptr,
                           const int* __restrict__ eidx,
                           const float* __restrict__ h,
                           const float* __restrict__ as,
                           const float* __restrict__ ad,
                           const float* __restrict__ b,
                           float* __restrict__ out, int n, int doRelu) {
  int wave = (blockIdx.x * blockDim.x + threadIdx.x) >> 6;
  int lane = threadIdx.x & 63;
  int nwaves = (gridDim.x * blockDim.x) >> 6;
  float bc = b[lane];
  for (int dst = wave; dst < n; dst += nwaves) {
    int lo = rowptr[dst], hi = rowptr[dst + 1];
    float adv = ad[dst];
    float m = -1e30f;
    for (int j = lo + lane; j < hi; j += 64) {
      float t = as[eidx[j]] + adv;
      t = (t > 0.f) ? t : NEG_SLOPE * t;
      m = fmaxf(m, t);
    }
#pragma unroll
    for (int off = 32; off; off >>= 1) m = fmaxf(m, __shfl_xor(m, off));
    float acc = 0.f, den = 0.f;
    for (int j = lo; j < hi; ++j) {
      int s = eidx[j];                        // wave-uniform
      float t = as[s] + adv;                  // broadcast load
      t = (t > 0.f) ? t : NEG_SLOPE * t;
      float w = expf(t - m);
      den += w;
      acc += w * h[(size_t)s * FH + lane];    // coalesced 256B gather
    }
    float o = acc / (den + EPS) + bc;
    if (doRelu) o = fmaxf(o, 0.f);
    out[(size_t)dst * FH + lane] = o;
  }
}

// ---------------- mean-pool per graph + final linear ----------------

__global__ void pool_kernel(const int* __restrict__ batch,
                            const float* __restrict__ h,
                            const float* __restrict__ Wlin,
                            const float* __restrict__ blin,
                            float* __restrict__ outp, int n, int ncls) {
  int g = blockIdx.x;
  __shared__ int sh[2];
  if (threadIdx.x == 0) {
    int lo = 0, hi = n;
    while (lo < hi) { int mid = (lo + hi) >> 1; if (batch[mid] < g) lo = mid + 1; else hi = mid; }
    sh[0] = lo;
    hi = n;
    while (lo < hi) { int mid = (lo + hi) >> 1; if (batch[mid] <= g) lo = mid + 1; else hi = mid; }
    sh[1] = lo;
  }
  __syncthreads();
  int lo = sh[0], hi = sh[1];
  int lane = threadIdx.x;  // blockDim = 64
  float acc = 0.f;
  for (int i = lo; i < hi; ++i) acc += h[(size_t)i * FH + lane];
  float pooled = acc / fmaxf((float)(hi - lo), 1.f);
  for (int k = 0; k < ncls; ++k) {
    float v = pooled * Wlin[lane * ncls + k];
#pragma unroll
    for (int off = 32; off; off >>= 1) v += __shfl_xor(v, off);
    if (lane == 0) outp[g * ncls + k] = v + blin[k];
  }
}

// ---------------- launch ----------------

extern "C" void kernel_launch(void* const* d_in, const int* in_sizes, int n_in,
                              void* d_out, int out_size, void* d_ws, size_t ws_size,
                              hipStream_t stream) {
  const float* x    = (const float*)d_in[0];
  const int*   ei   = (const int*)d_in[1];
  const int*   batch= (const int*)d_in[2];
  const float* W1   = (const float*)d_in[3];
  const float* as1  = (const float*)d_in[4];
  const float* ad1  = (const float*)d_in[5];
  const float* b1   = (const float*)d_in[6];
  const float* W2   = (const float*)d_in[7];
  const float* as2  = (const float*)d_in[8];
  const float* ad2  = (const float*)d_in[9];
  const float* b2   = (const float*)d_in[10];
  const float* Wlin = (const float*)d_in[11];
  const float* blin = (const float*)d_in[12];
  float* outp = (float*)d_out;

  const int N  = in_sizes[2];        // 50000
  const int E  = in_sizes[1] / 2;    // 800000
  const int ET = E + N;              // + self loops
  const int NCLS = 10;
  const int NG = out_size / NCLS;    // 512

  char* p = (char*)d_ws;
  auto alloc = [&](size_t bytes) {
    char* r = p;
    p += (bytes + 255) & ~(size_t)255;
    return r;
  };
  float* hA     = (float*)alloc((size_t)N * FH * 4);
  float* hB     = (float*)alloc((size_t)N * FH * 4);
  float* asb    = (float*)alloc((size_t)N * 4);
  float* adb    = (float*)alloc((size_t)N * 4);
  int*   deg    = (int*)alloc((size_t)N * 4);
  int*   rowptr = (int*)alloc((size_t)(N + 1) * 4);
  int*   cursor = (int*)alloc((size_t)N * 4);
  int*   eidx   = (int*)alloc((size_t)ET * 4);
  (void)ws_size; (void)n_in;

  const int TB = 256;

  // CSR by dst
  hipMemsetAsync(deg, 0, (size_t)N * 4, stream);
  hist_kernel<<<(ET + TB - 1) / TB, TB, 0, stream>>>(ei, deg, E, N);
  scan_kernel<<<1, 1024, 0, stream>>>(deg, rowptr, N);
  hipMemcpyAsync(cursor, rowptr, (size_t)N * 4, hipMemcpyDeviceToDevice, stream);
  scatter_kernel<<<(ET + TB - 1) / TB, TB, 0, stream>>>(ei, cursor, eidx, E, N);

  int aggBlocks = (N + 3) / 4;       // 4 waves/block, 1 wave/dst

  // gemm grid: 6250 row-groups of 8, 4 waves/block
  int gemmBlocks = (N / 8 + 3) / 4;  // 1563

  // layer 1
  gemm_alpha_kernel<128><<<gemmBlocks, TB, 0, stream>>>(x, W1, as1, ad1, hA, asb, adb, N);
  agg_kernel<<<aggBlocks, TB, 0, stream>>>(rowptr, eidx, hA, asb, adb, b1, hB, N, 1);

  // layer 2
  gemm_alpha_kernel<64><<<gemmBlocks, TB, 0, stream>>>(hB, W2, as2, ad2, hA, asb, adb, N);
  agg_kernel<<<aggBlocks, TB, 0, stream>>>(rowptr, eidx, hA, asb, adb, b2, hB, N, 0);

  // mean pool per graph + linear
  pool_kernel<<<NG, 64, 0, stream>>>(batch, hB, Wlin, blin, outp, N, NCLS);
}

// Round 8
// 549.846 us; speedup vs baseline: 1.8867x; 1.8867x over previous
//
#include <hip/hip_runtime.h>

// GAT (2-layer) + global mean pool + linear, MI355X.
// R1: gemm_alpha restructured — coalesced 8-row staging into wave-private LDS.
// R3 post-mortem: full unroll of k4 x 8-row loops exposed 256 LDS loads ->
// scheduler hoisted -> 256 VGPR + ~1.3GB scratch spill traffic -> 520us.
// R3 fix: #pragma unroll 2 on k4 loop + __launch_bounds__(256,2) VGPR cap 128.
// R4-R7: resubmission of R3 (broker timeouts — never benched).

constexpr int FH = 64;        // hidden/out feature width (both layers)
constexpr float NEG_SLOPE = 0.2f;
constexpr float EPS = 1e-16f;

// ---------------- CSR build ----------------

__global__ void hist_kernel(const int* __restrict__ ei, int* __restrict__ deg,
                            int E, int N) {
  int e = blockIdx.x * blockDim.x + threadIdx.x;
  if (e >= E + N) return;
  int dst = (e < E) ? ei[E + e] : (e - E);   // self-loops appended
  atomicAdd(&deg[dst], 1);
}

// single-block exclusive scan (n up to ~64k: 1024 threads, chunked)
__global__ void scan_kernel(const int* __restrict__ deg, int* __restrict__ rowptr,
                            int n) {
  __shared__ int buf[1024];
  __shared__ int carry;
  int t = threadIdx.x;
  if (t == 0) carry = 0;
  __syncthreads();
  for (int base = 0; base < n; base += 1024) {
    int i = base + t;
    int v = (i < n) ? deg[i] : 0;
    buf[t] = v;
    __syncthreads();
    for (int off = 1; off < 1024; off <<= 1) {
      int add = (t >= off) ? buf[t - off] : 0;
      __syncthreads();
      buf[t] += add;
      __syncthreads();
    }
    if (i < n) rowptr[i] = carry + buf[t] - v;   // exclusive
    __syncthreads();
    if (t == 0) carry += buf[1023];
    __syncthreads();
  }
  if (t == 0) rowptr[n] = carry;
}

__global__ void scatter_kernel(const int* __restrict__ ei, int* __restrict__ cursor,
                               int* __restrict__ eidx, int E, int N) {
  int e = blockIdx.x * blockDim.x + threadIdx.x;
  if (e >= E + N) return;
  int src, dst;
  if (e < E) { src = ei[e]; dst = ei[E + e]; }
  else       { src = dst = e - E; }
  int pos = atomicAdd(&cursor[dst], 1);
  eidx[pos] = src;
}

// ---------------- h = x @ W, plus alpha_s/alpha_d dot products ----------------
// Block = 256 threads = 4 waves. W staged in LDS once per block.
// Each wave owns 8 rows per group: lanes load the 8xFIN block COALESCED into a
// wave-private LDS buffer (no barrier: wave-synchronous), then compute with
// W[k][lane] LDS reads amortized over 8 rows of broadcast x reads.
// unroll 2 (NOT full): keeps <=16 float4 LDS reads in flight, no spill.

template <int FIN>
__global__ void __launch_bounds__(256, 2) gemm_alpha_kernel(
    const float* __restrict__ x, const float* __restrict__ W,
    const float* __restrict__ avs, const float* __restrict__ avd,
    float* __restrict__ h, float* __restrict__ as, float* __restrict__ ad,
    int n) {
  constexpr int K4 = FIN / 4;
  __shared__ float Wl[FIN][FH];              // 64 cols, row-major
  __shared__ float4 xbuf[4][8 * K4];         // per-wave [8 rows][FIN] as float4
  for (int i = threadIdx.x; i < FIN * FH; i += 256)
    Wl[i >> 6][i & 63] = W[i];
  __syncthreads();

  int wave = threadIdx.x >> 6;
  int lane = threadIdx.x & 63;
  float asc = avs[lane];
  float adc = avd[lane];
  float4* xb = xbuf[wave];
  int nw = gridDim.x * 4;
  int ngroups = n >> 3;                      // n = 50000 = 8*6250
  for (int g = blockIdx.x * 4 + wave; g < ngroups; g += nw) {
    int r0 = g << 3;
    const float4* xg = reinterpret_cast<const float4*>(x + (size_t)r0 * FIN);
    // coalesced stage: 8*K4 float4s, lane-strided
    for (int f = lane; f < 8 * K4; f += 64) xb[f] = xg[f];
    // wave-synchronous LDS RAW (compiler inserts lgkmcnt wait); no barrier
    float acc[8];
#pragma unroll
    for (int r = 0; r < 8; ++r) acc[r] = 0.f;
#pragma unroll 2
    for (int k4 = 0; k4 < K4; ++k4) {
      int k = k4 * 4;
      float w0 = Wl[k + 0][lane];
      float w1 = Wl[k + 1][lane];
      float w2 = Wl[k + 2][lane];
      float w3 = Wl[k + 3][lane];
#pragma unroll
      for (int r = 0; r < 8; ++r) {
        float4 xv = xb[r * K4 + k4];         // broadcast read, conflict-free
        acc[r] += xv.x * w0 + xv.y * w1 + xv.z * w2 + xv.w * w3;
      }
    }
#pragma unroll
    for (int r = 0; r < 8; ++r) {
      h[(size_t)(r0 + r) * FH + lane] = acc[r];
      float s = acc[r] * asc, d = acc[r] * adc;
#pragma unroll
      for (int off = 32; off; off >>= 1) {
        s += __shfl_xor(s, off);
        d += __shfl_xor(d, off);
      }
      if (lane == 0) { as[r0 + r] = s; ad[r0 + r] = d; }
    }
  }
}

// ---------------- per-dst softmax aggregation (gather) ----------------
// One wave per dst. Pass 1: lanes stride edges, reduce max(logit).
// Pass 2: serial edge loop; lane c owns feature c; denom redundant per lane.

__global__ void agg_kernel(const int* __restrict__ rowptr,
                           const int* __restrict__ eidx,
                           const float* __restrict__ h,
                           const float* __restrict__ as,
                           const float* __restrict__ ad,
                           const float* __restrict__ b,
                           float* __restrict__ out, int n, int doRelu) {
  int wave = (blockIdx.x * blockDim.x + threadIdx.x) >> 6;
  int lane = threadIdx.x & 63;
  int nwaves = (gridDim.x * blockDim.x) >> 6;
  float bc = b[lane];
  for (int dst = wave; dst < n; dst += nwaves) {
    int lo = rowptr[dst], hi = rowptr[dst + 1];
    float adv = ad[dst];
    float m = -1e30f;
    for (int j = lo + lane; j < hi; j += 64) {
      float t = as[eidx[j]] + adv;
      t = (t > 0.f) ? t : NEG_SLOPE * t;
      m = fmaxf(m, t);
    }
#pragma unroll
    for (int off = 32; off; off >>= 1) m = fmaxf(m, __shfl_xor(m, off));
    float acc = 0.f, den = 0.f;
    for (int j = lo; j < hi; ++j) {
      int s = eidx[j];                        // wave-uniform
      float t = as[s] + adv;                  // broadcast load
      t = (t > 0.f) ? t : NEG_SLOPE * t;
      float w = expf(t - m);
      den += w;
      acc += w * h[(size_t)s * FH + lane];    // coalesced 256B gather
    }
    float o = acc / (den + EPS) + bc;
    if (doRelu) o = fmaxf(o, 0.f);
    out[(size_t)dst * FH + lane] = o;
  }
}

// ---------------- mean-pool per graph + final linear ----------------

__global__ void pool_kernel(const int* __restrict__ batch,
                            const float* __restrict__ h,
                            const float* __restrict__ Wlin,
                            const float* __restrict__ blin,
                            float* __restrict__ outp, int n, int ncls) {
  int g = blockIdx.x;
  __shared__ int sh[2];
  if (threadIdx.x == 0) {
    int lo = 0, hi = n;
    while (lo < hi) { int mid = (lo + hi) >> 1; if (batch[mid] < g) lo = mid + 1; else hi = mid; }
    sh[0] = lo;
    hi = n;
    while (lo < hi) { int mid = (lo + hi) >> 1; if (batch[mid] <= g) lo = mid + 1; else hi = mid; }
    sh[1] = lo;
  }
  __syncthreads();
  int lo = sh[0], hi = sh[1];
  int lane = threadIdx.x;  // blockDim = 64
  float acc = 0.f;
  for (int i = lo; i < hi; ++i) acc += h[(size_t)i * FH + lane];
  float pooled = acc / fmaxf((float)(hi - lo), 1.f);
  for (int k = 0; k < ncls; ++k) {
    float v = pooled * Wlin[lane * ncls + k];
#pragma unroll
    for (int off = 32; off; off >>= 1) v += __shfl_xor(v, off);
    if (lane == 0) outp[g * ncls + k] = v + blin[k];
  }
}

// ---------------- launch ----------------

extern "C" void kernel_launch(void* const* d_in, const int* in_sizes, int n_in,
                              void* d_out, int out_size, void* d_ws, size_t ws_size,
                              hipStream_t stream) {
  const float* x    = (const float*)d_in[0];
  const int*   ei   = (const int*)d_in[1];
  const int*   batch= (const int*)d_in[2];
  const float* W1   = (const float*)d_in[3];
  const float* as1  = (const float*)d_in[4];
  const float* ad1  = (const float*)d_in[5];
  const float* b1   = (const float*)d_in[6];
  const float* W2   = (const float*)d_in[7];
  const float* as2  = (const float*)d_in[8];
  const float* ad2  = (const float*)d_in[9];
  const float* b2   = (const float*)d_in[10];
  const float* Wlin = (const float*)d_in[11];
  const float* blin = (const float*)d_in[12];
  float* outp = (float*)d_out;

  const int N  = in_sizes[2];        // 50000
  const int E  = in_sizes[1] / 2;    // 800000
  const int ET = E + N;              // + self loops
  const int NCLS = 10;
  const int NG = out_size / NCLS;    // 512

  char* p = (char*)d_ws;
  auto alloc = [&](size_t bytes) {
    char* r = p;
    p += (bytes + 255) & ~(size_t)255;
    return r;
  };
  float* hA     = (float*)alloc((size_t)N * FH * 4);
  float* hB     = (float*)alloc((size_t)N * FH * 4);
  float* asb    = (float*)alloc((size_t)N * 4);
  float* adb    = (float*)alloc((size_t)N * 4);
  int*   deg    = (int*)alloc((size_t)N * 4);
  int*   rowptr = (int*)alloc((size_t)(N + 1) * 4);
  int*   cursor = (int*)alloc((size_t)N * 4);
  int*   eidx   = (int*)alloc((size_t)ET * 4);
  (void)ws_size; (void)n_in;

  const int TB = 256;

  // CSR by dst
  hipMemsetAsync(deg, 0, (size_t)N * 4, stream);
  hist_kernel<<<(ET + TB - 1) / TB, TB, 0, stream>>>(ei, deg, E, N);
  scan_kernel<<<1, 1024, 0, stream>>>(deg, rowptr, N);
  hipMemcpyAsync(cursor, rowptr, (size_t)N * 4, hipMemcpyDeviceToDevice, stream);
  scatter_kernel<<<(ET + TB - 1) / TB, TB, 0, stream>>>(ei, cursor, eidx, E, N);

  int aggBlocks = (N + 3) / 4;       // 4 waves/block, 1 wave/dst

  // gemm grid: 6250 row-groups of 8, 4 waves/block
  int gemmBlocks = (N / 8 + 3) / 4;  // 1563

  // layer 1
  gemm_alpha_kernel<128><<<gemmBlocks, TB, 0, stream>>>(x, W1, as1, ad1, hA, asb, adb, N);
  agg_kernel<<<aggBlocks, TB, 0, stream>>>(rowptr, eidx, hA, asb, adb, b1, hB, N, 1);

  // layer 2
  gemm_alpha_kernel<64><<<gemmBlocks, TB, 0, stream>>>(hB, W2, as2, ad2, hA, asb, adb, N);
  agg_kernel<<<aggBlocks, TB, 0, stream>>>(rowptr, eidx, hA, asb, adb, b2, hB, N, 0);

  // mean pool per graph + linear
  pool_kernel<<<NG, 64, 0, stream>>>(batch, hB, Wlin, blin, outp, N, NCLS);
}

// Round 9
// 374.582 us; speedup vs baseline: 2.7694x; 1.4679x over previous
//
#include <hip/hip_runtime.h>

// GAT (2-layer) + global mean pool + linear, MI355X.
// R3 (measured): gemm spill fixed -> 550us total; agg 95.5us x2 latency-bound
//   (serial per-dst edge chain, 1 outstanding gather); ~360us unprofiled,
//   single-block scan suspected.
// R8: (A) agg 4-way edge-parallel float4 gather (4 load chains in flight),
//     (B) 3-dispatch parallel scan replacing single-block scan (+ writes cursor).

constexpr int FH = 64;        // hidden/out feature width (both layers)
constexpr float NEG_SLOPE = 0.2f;
constexpr float EPS = 1e-16f;

// ---------------- CSR build ----------------

__global__ void hist_kernel(const int* __restrict__ ei, int* __restrict__ deg,
                            int E, int N) {
  int e = blockIdx.x * blockDim.x + threadIdx.x;
  if (e >= E + N) return;
  int dst = (e < E) ? ei[E + e] : (e - E);   // self-loops appended
  atomicAdd(&deg[dst], 1);
}

// --- parallel exclusive scan over n<=64*1024 ints, 3 dispatches ---
// A: per-block (1024) local exclusive scan into rowptr, block sums to partial[]
__global__ void scan_local_kernel(const int* __restrict__ deg,
                                  int* __restrict__ rowptr,
                                  int* __restrict__ partial, int n) {
  __shared__ int buf[1024];
  int t = threadIdx.x;
  int i = blockIdx.x * 1024 + t;
  int v = (i < n) ? deg[i] : 0;
  buf[t] = v;
  __syncthreads();
  for (int off = 1; off < 1024; off <<= 1) {
    int add = (t >= off) ? buf[t - off] : 0;
    __syncthreads();
    buf[t] += add;
    __syncthreads();
  }
  if (i < n) rowptr[i] = buf[t] - v;          // exclusive, block-local
  if (t == 1023) partial[blockIdx.x] = buf[1023];
}

// B: inclusive scan of <=64 block partials, one wave
__global__ void scan_partial_kernel(int* __restrict__ partial, int nb) {
  int t = threadIdx.x;                        // blockDim = 64
  int v = (t < nb) ? partial[t] : 0;
#pragma unroll
  for (int off = 1; off < 64; off <<= 1) {
    int u = __shfl_up(v, off);
    if (t >= off) v += u;
  }
  if (t < nb) partial[t] = v;
}

// C: add block offsets; also write cursor copy and rowptr[n]
__global__ void scan_add_kernel(int* __restrict__ rowptr,
                                int* __restrict__ cursor,
                                const int* __restrict__ partial, int n, int nb) {
  int i = blockIdx.x * 1024 + threadIdx.x;
  int off = (blockIdx.x > 0) ? partial[blockIdx.x - 1] : 0;
  if (i < n) {
    int r = rowptr[i] + off;
    rowptr[i] = r;
    cursor[i] = r;
  }
  if (i == n) rowptr[n] = partial[nb - 1];
}

__global__ void scatter_kernel(const int* __restrict__ ei, int* __restrict__ cursor,
                               int* __restrict__ eidx, int E, int N) {
  int e = blockIdx.x * blockDim.x + threadIdx.x;
  if (e >= E + N) return;
  int src, dst;
  if (e < E) { src = ei[e]; dst = ei[E + e]; }
  else       { src = dst = e - E; }
  int pos = atomicAdd(&cursor[dst], 1);
  eidx[pos] = src;
}

// ---------------- h = x @ W, plus alpha_s/alpha_d dot products ----------------
// (unchanged from R3 — spill-fixed version)

template <int FIN>
__global__ void __launch_bounds__(256, 2) gemm_alpha_kernel(
    const float* __restrict__ x, const float* __restrict__ W,
    const float* __restrict__ avs, const float* __restrict__ avd,
    float* __restrict__ h, float* __restrict__ as, float* __restrict__ ad,
    int n) {
  constexpr int K4 = FIN / 4;
  __shared__ float Wl[FIN][FH];              // 64 cols, row-major
  __shared__ float4 xbuf[4][8 * K4];         // per-wave [8 rows][FIN] as float4
  for (int i = threadIdx.x; i < FIN * FH; i += 256)
    Wl[i >> 6][i & 63] = W[i];
  __syncthreads();

  int wave = threadIdx.x >> 6;
  int lane = threadIdx.x & 63;
  float asc = avs[lane];
  float adc = avd[lane];
  float4* xb = xbuf[wave];
  int nw = gridDim.x * 4;
  int ngroups = n >> 3;                      // n = 50000 = 8*6250
  for (int g = blockIdx.x * 4 + wave; g < ngroups; g += nw) {
    int r0 = g << 3;
    const float4* xg = reinterpret_cast<const float4*>(x + (size_t)r0 * FIN);
    for (int f = lane; f < 8 * K4; f += 64) xb[f] = xg[f];
    float acc[8];
#pragma unroll
    for (int r = 0; r < 8; ++r) acc[r] = 0.f;
#pragma unroll 2
    for (int k4 = 0; k4 < K4; ++k4) {
      int k = k4 * 4;
      float w0 = Wl[k + 0][lane];
      float w1 = Wl[k + 1][lane];
      float w2 = Wl[k + 2][lane];
      float w3 = Wl[k + 3][lane];
#pragma unroll
      for (int r = 0; r < 8; ++r) {
        float4 xv = xb[r * K4 + k4];
        acc[r] += xv.x * w0 + xv.y * w1 + xv.z * w2 + xv.w * w3;
      }
    }
#pragma unroll
    for (int r = 0; r < 8; ++r) {
      h[(size_t)(r0 + r) * FH + lane] = acc[r];
      float s = acc[r] * asc, d = acc[r] * adc;
#pragma unroll
      for (int off = 32; off; off >>= 1) {
        s += __shfl_xor(s, off);
        d += __shfl_xor(d, off);
      }
      if (lane == 0) { as[r0 + r] = s; ad[r0 + r] = d; }
    }
  }
}

// ---------------- per-dst softmax aggregation (gather) ----------------
// One wave per dst. Pass 1 (unchanged): 64-edge-parallel max reduce.
// Pass 2 (R8): lane = (edge-slot eq = lane>>4) x (feature-quad fq = lane&15).
// Each 16-lane group handles every 4th edge with a float4 h-gather ->
// 4 independent load chains in flight per wave (was 1 serial chain).
// Combine groups with 2 shfl_xor steps; lanes eq==0 store the row.

__global__ void agg_kernel(const int* __restrict__ rowptr,
                           const int* __restrict__ eidx,
                           const float* __restrict__ h,
                           const float* __restrict__ as,
                           const float* __restrict__ ad,
                           const float* __restrict__ b,
                           float* __restrict__ out, int n, int doRelu) {
  int wave = (blockIdx.x * blockDim.x + threadIdx.x) >> 6;
  int lane = threadIdx.x & 63;
  int nwaves = (gridDim.x * blockDim.x) >> 6;
  int eq = lane >> 4;                         // edge slot 0..3
  int fq = lane & 15;                         // feature quad 0..15
  const float4* h4 = reinterpret_cast<const float4*>(h);
  float4 bc = reinterpret_cast<const float4*>(b)[fq];
  for (int dst = wave; dst < n; dst += nwaves) {
    int lo = rowptr[dst], hi = rowptr[dst + 1];
    float adv = ad[dst];
    // pass 1: max logit, 64-edge-parallel
    float m = -1e30f;
    for (int j = lo + lane; j < hi; j += 64) {
      float t = as[eidx[j]] + adv;
      t = (t > 0.f) ? t : NEG_SLOPE * t;
      m = fmaxf(m, t);
    }
#pragma unroll
    for (int off = 32; off; off >>= 1) m = fmaxf(m, __shfl_xor(m, off));
    // pass 2: 4 edges concurrently, float4 gathers
    float4 acc = {0.f, 0.f, 0.f, 0.f};
    float den = 0.f;
    for (int j = lo + eq; j < hi; j += 4) {
      int s = eidx[j];                        // group-uniform broadcast load
      float t = as[s] + adv;
      t = (t > 0.f) ? t : NEG_SLOPE * t;
      float w = __expf(t - m);
      den += w;
      float4 hv = h4[(size_t)s * 16 + fq];    // 16-lane x 16B = 256B gather
      acc.x += w * hv.x;
      acc.y += w * hv.y;
      acc.z += w * hv.z;
      acc.w += w * hv.w;
    }
    // combine the 4 edge groups (lanes {fq, fq+16, fq+32, fq+48})
#pragma unroll
    for (int off = 16; off < 64; off <<= 1) {
      acc.x += __shfl_xor(acc.x, off);
      acc.y += __shfl_xor(acc.y, off);
      acc.z += __shfl_xor(acc.z, off);
      acc.w += __shfl_xor(acc.w, off);
      den   += __shfl_xor(den, off);
    }
    if (eq == 0) {
      float inv = 1.f / (den + EPS);
      float4 o;
      o.x = acc.x * inv + bc.x;
      o.y = acc.y * inv + bc.y;
      o.z = acc.z * inv + bc.z;
      o.w = acc.w * inv + bc.w;
      if (doRelu) {
        o.x = fmaxf(o.x, 0.f); o.y = fmaxf(o.y, 0.f);
        o.z = fmaxf(o.z, 0.f); o.w = fmaxf(o.w, 0.f);
      }
      reinterpret_cast<float4*>(out)[(size_t)dst * 16 + fq] = o;
    }
  }
}

// ---------------- mean-pool per graph + final linear ----------------

__global__ void pool_kernel(const int* __restrict__ batch,
                            const float* __restrict__ h,
                            const float* __restrict__ Wlin,
                            const float* __restrict__ blin,
                            float* __restrict__ outp, int n, int ncls) {
  int g = blockIdx.x;
  __shared__ int sh[2];
  if (threadIdx.x == 0) {
    int lo = 0, hi = n;
    while (lo < hi) { int mid = (lo + hi) >> 1; if (batch[mid] < g) lo = mid + 1; else hi = mid; }
    sh[0] = lo;
    hi = n;
    while (lo < hi) { int mid = (lo + hi) >> 1; if (batch[mid] <= g) lo = mid + 1; else hi = mid; }
    sh[1] = lo;
  }
  __syncthreads();
  int lo = sh[0], hi = sh[1];
  int lane = threadIdx.x;  // blockDim = 64
  float acc = 0.f;
  for (int i = lo; i < hi; ++i) acc += h[(size_t)i * FH + lane];
  float pooled = acc / fmaxf((float)(hi - lo), 1.f);
  for (int k = 0; k < ncls; ++k) {
    float v = pooled * Wlin[lane * ncls + k];
#pragma unroll
    for (int off = 32; off; off >>= 1) v += __shfl_xor(v, off);
    if (lane == 0) outp[g * ncls + k] = v + blin[k];
  }
}

// ---------------- launch ----------------

extern "C" void kernel_launch(void* const* d_in, const int* in_sizes, int n_in,
                              void* d_out, int out_size, void* d_ws, size_t ws_size,
                              hipStream_t stream) {
  const float* x    = (const float*)d_in[0];
  const int*   ei   = (const int*)d_in[1];
  const int*   batch= (const int*)d_in[2];
  const float* W1   = (const float*)d_in[3];
  const float* as1  = (const float*)d_in[4];
  const float* ad1  = (const float*)d_in[5];
  const float* b1   = (const float*)d_in[6];
  const float* W2   = (const float*)d_in[7];
  const float* as2  = (const float*)d_in[8];
  const float* ad2  = (const float*)d_in[9];
  const float* b2   = (const float*)d_in[10];
  const float* Wlin = (const float*)d_in[11];
  const float* blin = (const float*)d_in[12];
  float* outp = (float*)d_out;

  const int N  = in_sizes[2];        // 50000
  const int E  = in_sizes[1] / 2;    // 800000
  const int ET = E + N;              // + self loops
  const int NCLS = 10;
  const int NG = out_size / NCLS;    // 512

  char* p = (char*)d_ws;
  auto alloc = [&](size_t bytes) {
    char* r = p;
    p += (bytes + 255) & ~(size_t)255;
    return r;
  };
  float* hA      = (float*)alloc((size_t)N * FH * 4);
  float* hB      = (float*)alloc((size_t)N * FH * 4);
  float* asb     = (float*)alloc((size_t)N * 4);
  float* adb     = (float*)alloc((size_t)N * 4);
  int*   deg     = (int*)alloc((size_t)N * 4);
  int*   rowptr  = (int*)alloc((size_t)(N + 1) * 4);
  int*   cursor  = (int*)alloc((size_t)N * 4);
  int*   eidx    = (int*)alloc((size_t)ET * 4);
  int*   partial = (int*)alloc(64 * 4);
  (void)ws_size; (void)n_in;

  const int TB = 256;
  const int nb = (N + 1023) / 1024;  // 49 scan blocks (<=64 required)

  // CSR by dst
  hipMemsetAsync(deg, 0, (size_t)N * 4, stream);
  hist_kernel<<<(ET + TB - 1) / TB, TB, 0, stream>>>(ei, deg, E, N);
  scan_local_kernel<<<nb, 1024, 0, stream>>>(deg, rowptr, partial, N);
  scan_partial_kernel<<<1, 64, 0, stream>>>(partial, nb);
  scan_add_kernel<<<nb, 1024, 0, stream>>>(rowptr, cursor, partial, N, nb);
  scatter_kernel<<<(ET + TB - 1) / TB, TB, 0, stream>>>(ei, cursor, eidx, E, N);

  int aggBlocks = (N + 3) / 4;       // 4 waves/block, 1 wave/dst
  int gemmBlocks = (N / 8 + 3) / 4;  // 1563

  // layer 1
  gemm_alpha_kernel<128><<<gemmBlocks, TB, 0, stream>>>(x, W1, as1, ad1, hA, asb, adb, N);
  agg_kernel<<<aggBlocks, TB, 0, stream>>>(rowptr, eidx, hA, asb, adb, b1, hB, N, 1);

  // layer 2
  gemm_alpha_kernel<64><<<gemmBlocks, TB, 0, stream>>>(hB, W2, as2, ad2, hA, asb, adb, N);
  agg_kernel<<<aggBlocks, TB, 0, stream>>>(rowptr, eidx, hA, asb, adb, b2, hB, N, 0);

  // mean pool per graph + linear
  pool_kernel<<<NG, 64, 0, stream>>>(batch, hB, Wlin, blin, outp, N, NCLS);
}

// Round 13
// 329.836 us; speedup vs baseline: 3.1451x; 1.1357x over previous
//
#include <hip/hip_runtime.h>

// GAT (2-layer) + global mean pool + linear, MI355X.
// R8 (measured): total 374.6us; scatter_kernel tops at ~60us — WRITE 54.7MB
//   (16x line-thrash on random 4B eidx writes) + 850k atomic RMW on cursor.
// R9: rank-trick CSR build — hist's atomicAdd return value IS the edge's
//   intra-dst rank (softmax agg is permutation-invariant). Scatter becomes
//   atomic-free: pos = rowptr[dst] + rank[e]. cursor eliminated.
// R10-R12: resubmission of R9 (broker timeouts — never benched).

constexpr int FH = 64;        // hidden/out feature width (both layers)
constexpr float NEG_SLOPE = 0.2f;
constexpr float EPS = 1e-16f;

// ---------------- CSR build ----------------

// hist + rank: deg[dst]++ and record this edge's arrival order within dst
__global__ void hist_kernel(const int* __restrict__ ei, int* __restrict__ deg,
                            int* __restrict__ rank, int E, int N) {
  int e = blockIdx.x * blockDim.x + threadIdx.x;
  if (e >= E + N) return;
  int dst = (e < E) ? ei[E + e] : (e - E);   // self-loops appended
  rank[e] = atomicAdd(&deg[dst], 1);
}

// --- parallel exclusive scan over n<=64*1024 ints, 3 dispatches ---
__global__ void scan_local_kernel(const int* __restrict__ deg,
                                  int* __restrict__ rowptr,
                                  int* __restrict__ partial, int n) {
  __shared__ int buf[1024];
  int t = threadIdx.x;
  int i = blockIdx.x * 1024 + t;
  int v = (i < n) ? deg[i] : 0;
  buf[t] = v;
  __syncthreads();
  for (int off = 1; off < 1024; off <<= 1) {
    int add = (t >= off) ? buf[t - off] : 0;
    __syncthreads();
    buf[t] += add;
    __syncthreads();
  }
  if (i < n) rowptr[i] = buf[t] - v;          // exclusive, block-local
  if (t == 1023) partial[blockIdx.x] = buf[1023];
}

__global__ void scan_partial_kernel(int* __restrict__ partial, int nb) {
  int t = threadIdx.x;                        // blockDim = 64
  int v = (t < nb) ? partial[t] : 0;
#pragma unroll
  for (int off = 1; off < 64; off <<= 1) {
    int u = __shfl_up(v, off);
    if (t >= off) v += u;
  }
  if (t < nb) partial[t] = v;
}

__global__ void scan_add_kernel(int* __restrict__ rowptr,
                                const int* __restrict__ partial, int n, int nb) {
  int i = blockIdx.x * 1024 + threadIdx.x;
  int off = (blockIdx.x > 0) ? partial[blockIdx.x - 1] : 0;
  if (i < n) rowptr[i] += off;
  if (i == n) rowptr[n] = partial[nb - 1];
}

// atomic-free scatter: pos = rowptr[dst] + rank[e]
__global__ void scatter_kernel(const int* __restrict__ ei,
                               const int* __restrict__ rowptr,
                               const int* __restrict__ rank,
                               int* __restrict__ eidx, int E, int N) {
  int e = blockIdx.x * blockDim.x + threadIdx.x;
  if (e >= E + N) return;
  int src, dst;
  if (e < E) { src = ei[e]; dst = ei[E + e]; }
  else       { src = dst = e - E; }
  eidx[rowptr[dst] + rank[e]] = src;
}

// ---------------- h = x @ W, plus alpha_s/alpha_d dot products ----------------
// (unchanged from R3 — spill-fixed version)

template <int FIN>
__global__ void __launch_bounds__(256, 2) gemm_alpha_kernel(
    const float* __restrict__ x, const float* __restrict__ W,
    const float* __restrict__ avs, const float* __restrict__ avd,
    float* __restrict__ h, float* __restrict__ as, float* __restrict__ ad,
    int n) {
  constexpr int K4 = FIN / 4;
  __shared__ float Wl[FIN][FH];              // 64 cols, row-major
  __shared__ float4 xbuf[4][8 * K4];         // per-wave [8 rows][FIN] as float4
  for (int i = threadIdx.x; i < FIN * FH; i += 256)
    Wl[i >> 6][i & 63] = W[i];
  __syncthreads();

  int wave = threadIdx.x >> 6;
  int lane = threadIdx.x & 63;
  float asc = avs[lane];
  float adc = avd[lane];
  float4* xb = xbuf[wave];
  int nw = gridDim.x * 4;
  int ngroups = n >> 3;                      // n = 50000 = 8*6250
  for (int g = blockIdx.x * 4 + wave; g < ngroups; g += nw) {
    int r0 = g << 3;
    const float4* xg = reinterpret_cast<const float4*>(x + (size_t)r0 * FIN);
    for (int f = lane; f < 8 * K4; f += 64) xb[f] = xg[f];
    float acc[8];
#pragma unroll
    for (int r = 0; r < 8; ++r) acc[r] = 0.f;
#pragma unroll 2
    for (int k4 = 0; k4 < K4; ++k4) {
      int k = k4 * 4;
      float w0 = Wl[k + 0][lane];
      float w1 = Wl[k + 1][lane];
      float w2 = Wl[k + 2][lane];
      float w3 = Wl[k + 3][lane];
#pragma unroll
      for (int r = 0; r < 8; ++r) {
        float4 xv = xb[r * K4 + k4];
        acc[r] += xv.x * w0 + xv.y * w1 + xv.z * w2 + xv.w * w3;
      }
    }
#pragma unroll
    for (int r = 0; r < 8; ++r) {
      h[(size_t)(r0 + r) * FH + lane] = acc[r];
      float s = acc[r] * asc, d = acc[r] * adc;
#pragma unroll
      for (int off = 32; off; off >>= 1) {
        s += __shfl_xor(s, off);
        d += __shfl_xor(d, off);
      }
      if (lane == 0) { as[r0 + r] = s; ad[r0 + r] = d; }
    }
  }
}

// ---------------- per-dst softmax aggregation (gather) ----------------
// (unchanged from R8 — 4-way edge-parallel float4 gather)

__global__ void agg_kernel(const int* __restrict__ rowptr,
                           const int* __restrict__ eidx,
                           const float* __restrict__ h,
                           const float* __restrict__ as,
                           const float* __restrict__ ad,
                           const float* __restrict__ b,
                           float* __restrict__ out, int n, int doRelu) {
  int wave = (blockIdx.x * blockDim.x + threadIdx.x) >> 6;
  int lane = threadIdx.x & 63;
  int nwaves = (gridDim.x * blockDim.x) >> 6;
  int eq = lane >> 4;                         // edge slot 0..3
  int fq = lane & 15;                         // feature quad 0..15
  const float4* h4 = reinterpret_cast<const float4*>(h);
  float4 bc = reinterpret_cast<const float4*>(b)[fq];
  for (int dst = wave; dst < n; dst += nwaves) {
    int lo = rowptr[dst], hi = rowptr[dst + 1];
    float adv = ad[dst];
    // pass 1: max logit, 64-edge-parallel
    float m = -1e30f;
    for (int j = lo + lane; j < hi; j += 64) {
      float t = as[eidx[j]] + adv;
      t = (t > 0.f) ? t : NEG_SLOPE * t;
      m = fmaxf(m, t);
    }
#pragma unroll
    for (int off = 32; off; off >>= 1) m = fmaxf(m, __shfl_xor(m, off));
    // pass 2: 4 edges concurrently, float4 gathers
    float4 acc = {0.f, 0.f, 0.f, 0.f};
    float den = 0.f;
    for (int j = lo + eq; j < hi; j += 4) {
      int s = eidx[j];                        // group-uniform broadcast load
      float t = as[s] + adv;
      t = (t > 0.f) ? t : NEG_SLOPE * t;
      float w = __expf(t - m);
      den += w;
      float4 hv = h4[(size_t)s * 16 + fq];    // 16-lane x 16B = 256B gather
      acc.x += w * hv.x;
      acc.y += w * hv.y;
      acc.z += w * hv.z;
      acc.w += w * hv.w;
    }
    // combine the 4 edge groups (lanes {fq, fq+16, fq+32, fq+48})
#pragma unroll
    for (int off = 16; off < 64; off <<= 1) {
      acc.x += __shfl_xor(acc.x, off);
      acc.y += __shfl_xor(acc.y, off);
      acc.z += __shfl_xor(acc.z, off);
      acc.w += __shfl_xor(acc.w, off);
      den   += __shfl_xor(den, off);
    }
    if (eq == 0) {
      float inv = 1.f / (den + EPS);
      float4 o;
      o.x = acc.x * inv + bc.x;
      o.y = acc.y * inv + bc.y;
      o.z = acc.z * inv + bc.z;
      o.w = acc.w * inv + bc.w;
      if (doRelu) {
        o.x = fmaxf(o.x, 0.f); o.y = fmaxf(o.y, 0.f);
        o.z = fmaxf(o.z, 0.f); o.w = fmaxf(o.w, 0.f);
      }
      reinterpret_cast<float4*>(out)[(size_t)dst * 16 + fq] = o;
    }
  }
}

// ---------------- mean-pool per graph + final linear ----------------

__global__ void pool_kernel(const int* __restrict__ batch,
                            const float* __restrict__ h,
                            const float* __restrict__ Wlin,
                            const float* __restrict__ blin,
                            float* __restrict__ outp, int n, int ncls) {
  int g = blockIdx.x;
  __shared__ int sh[2];
  if (threadIdx.x == 0) {
    int lo = 0, hi = n;
    while (lo < hi) { int mid = (lo + hi) >> 1; if (batch[mid] < g) lo = mid + 1; else hi = mid; }
    sh[0] = lo;
    hi = n;
    while (lo < hi) { int mid = (lo + hi) >> 1; if (batch[mid] <= g) lo = mid + 1; else hi = mid; }
    sh[1] = lo;
  }
  __syncthreads();
  int lo = sh[0], hi = sh[1];
  int lane = threadIdx.x;  // blockDim = 64
  float acc = 0.f;
  for (int i = lo; i < hi; ++i) acc += h[(size_t)i * FH + lane];
  float pooled = acc / fmaxf((float)(hi - lo), 1.f);
  for (int k = 0; k < ncls; ++k) {
    float v = pooled * Wlin[lane * ncls + k];
#pragma unroll
    for (int off = 32; off; off >>= 1) v += __shfl_xor(v, off);
    if (lane == 0) outp[g * ncls + k] = v + blin[k];
  }
}

// ---------------- launch ----------------

extern "C" void kernel_launch(void* const* d_in, const int* in_sizes, int n_in,
                              void* d_out, int out_size, void* d_ws, size_t ws_size,
                              hipStream_t stream) {
  const float* x    = (const float*)d_in[0];
  const int*   ei   = (const int*)d_in[1];
  const int*   batch= (const int*)d_in[2];
  const float* W1   = (const float*)d_in[3];
  const float* as1  = (const float*)d_in[4];
  const float* ad1  = (const float*)d_in[5];
  const float* b1   = (const float*)d_in[6];
  const float* W2   = (const float*)d_in[7];
  const float* as2  = (const float*)d_in[8];
  const float* ad2  = (const float*)d_in[9];
  const float* b2   = (const float*)d_in[10];
  const float* Wlin = (const float*)d_in[11];
  const float* blin = (const float*)d_in[12];
  float* outp = (float*)d_out;

  const int N  = in_sizes[2];        // 50000
  const int E  = in_sizes[1] / 2;    // 800000
  const int ET = E + N;              // + self loops
  const int NCLS = 10;
  const int NG = out_size / NCLS;    // 512

  char* p = (char*)d_ws;
  auto alloc = [&](size_t bytes) {
    char* r = p;
    p += (bytes + 255) & ~(size_t)255;
    return r;
  };
  float* hA      = (float*)alloc((size_t)N * FH * 4);
  float* hB      = (float*)alloc((size_t)N * FH * 4);
  float* asb     = (float*)alloc((size_t)N * 4);
  float* adb     = (float*)alloc((size_t)N * 4);
  int*   deg     = (int*)alloc((size_t)N * 4);
  int*   rowptr  = (int*)alloc((size_t)(N + 1) * 4);
  int*   rank    = (int*)alloc((size_t)ET * 4);
  int*   eidx    = (int*)alloc((size_t)ET * 4);
  int*   partial = (int*)alloc(64 * 4);
  (void)ws_size; (void)n_in;

  const int TB = 256;
  const int nb = (N + 1023) / 1024;  // 49 scan blocks (<=64 required)

  // CSR by dst (atomic-free scatter via rank trick)
  hipMemsetAsync(deg, 0, (size_t)N * 4, stream);
  hist_kernel<<<(ET + TB - 1) / TB, TB, 0, stream>>>(ei, deg, rank, E, N);
  scan_local_kernel<<<nb, 1024, 0, stream>>>(deg, rowptr, partial, N);
  scan_partial_kernel<<<1, 64, 0, stream>>>(partial, nb);
  scan_add_kernel<<<nb, 1024, 0, stream>>>(rowptr, partial, N, nb);
  scatter_kernel<<<(ET + TB - 1) / TB, TB, 0, stream>>>(ei, rowptr, rank, eidx, E, N);

  int aggBlocks = (N + 3) / 4;       // 4 waves/block, 1 wave/dst
  int gemmBlocks = (N / 8 + 3) / 4;  // 1563

  // layer 1
  gemm_alpha_kernel<128><<<gemmBlocks, TB, 0, stream>>>(x, W1, as1, ad1, hA, asb, adb, N);
  agg_kernel<<<aggBlocks, TB, 0, stream>>>(rowptr, eidx, hA, asb, adb, b1, hB, N, 1);

  // layer 2
  gemm_alpha_kernel<64><<<gemmBlocks, TB, 0, stream>>>(hB, W2, as2, ad2, hA, asb, adb, N);
  agg_kernel<<<aggBlocks, TB, 0, stream>>>(rowptr, eidx, hA, asb, adb, b2, hB, N, 0);

  // mean pool per graph + linear
  pool_kernel<<<NG, 64, 0, stream>>>(batch, hB, Wlin, blin, outp, N, NCLS);
}

// Round 16
// 300.144 us; speedup vs baseline: 3.4563x; 1.0989x over previous
//
#include <hip/hip_runtime.h>

// GAT (2-layer) + global mean pool + linear, MI355X.
// R9/R13 (measured): total 329.8us; rank-trick scatter confirmed (out of top-5).
//   New top: pool_kernel 46.9us — 512 blocks x 1 wave = 2 waves/CU (occ 3.9%),
//   ~98 serial scalar row-loads per graph = latency-bound.
// R13 fix: pool v2 — 4 waves/block, lane=(rs,fq) split: 16 rows in flight,
//   float4 loads; shfl_xor(16,32) + LDS combine -> pooled[64] -> linear.
// R14/R15: resubmission of R13 (broker timeouts — never benched).

constexpr int FH = 64;        // hidden/out feature width (both layers)
constexpr float NEG_SLOPE = 0.2f;
constexpr float EPS = 1e-16f;

// ---------------- CSR build ----------------

// hist + rank: deg[dst]++ and record this edge's arrival order within dst
__global__ void hist_kernel(const int* __restrict__ ei, int* __restrict__ deg,
                            int* __restrict__ rank, int E, int N) {
  int e = blockIdx.x * blockDim.x + threadIdx.x;
  if (e >= E + N) return;
  int dst = (e < E) ? ei[E + e] : (e - E);   // self-loops appended
  rank[e] = atomicAdd(&deg[dst], 1);
}

// --- parallel exclusive scan over n<=64*1024 ints, 3 dispatches ---
__global__ void scan_local_kernel(const int* __restrict__ deg,
                                  int* __restrict__ rowptr,
                                  int* __restrict__ partial, int n) {
  __shared__ int buf[1024];
  int t = threadIdx.x;
  int i = blockIdx.x * 1024 + t;
  int v = (i < n) ? deg[i] : 0;
  buf[t] = v;
  __syncthreads();
  for (int off = 1; off < 1024; off <<= 1) {
    int add = (t >= off) ? buf[t - off] : 0;
    __syncthreads();
    buf[t] += add;
    __syncthreads();
  }
  if (i < n) rowptr[i] = buf[t] - v;          // exclusive, block-local
  if (t == 1023) partial[blockIdx.x] = buf[1023];
}

__global__ void scan_partial_kernel(int* __restrict__ partial, int nb) {
  int t = threadIdx.x;                        // blockDim = 64
  int v = (t < nb) ? partial[t] : 0;
#pragma unroll
  for (int off = 1; off < 64; off <<= 1) {
    int u = __shfl_up(v, off);
    if (t >= off) v += u;
  }
  if (t < nb) partial[t] = v;
}

__global__ void scan_add_kernel(int* __restrict__ rowptr,
                                const int* __restrict__ partial, int n, int nb) {
  int i = blockIdx.x * 1024 + threadIdx.x;
  int off = (blockIdx.x > 0) ? partial[blockIdx.x - 1] : 0;
  if (i < n) rowptr[i] += off;
  if (i == n) rowptr[n] = partial[nb - 1];
}

// atomic-free scatter: pos = rowptr[dst] + rank[e]
__global__ void scatter_kernel(const int* __restrict__ ei,
                               const int* __restrict__ rowptr,
                               const int* __restrict__ rank,
                               int* __restrict__ eidx, int E, int N) {
  int e = blockIdx.x * blockDim.x + threadIdx.x;
  if (e >= E + N) return;
  int src, dst;
  if (e < E) { src = ei[e]; dst = ei[E + e]; }
  else       { src = dst = e - E; }
  eidx[rowptr[dst] + rank[e]] = src;
}

// ---------------- h = x @ W, plus alpha_s/alpha_d dot products ----------------
// (unchanged from R3 — spill-fixed version)

template <int FIN>
__global__ void __launch_bounds__(256, 2) gemm_alpha_kernel(
    const float* __restrict__ x, const float* __restrict__ W,
    const float* __restrict__ avs, const float* __restrict__ avd,
    float* __restrict__ h, float* __restrict__ as, float* __restrict__ ad,
    int n) {
  constexpr int K4 = FIN / 4;
  __shared__ float Wl[FIN][FH];              // 64 cols, row-major
  __shared__ float4 xbuf[4][8 * K4];         // per-wave [8 rows][FIN] as float4
  for (int i = threadIdx.x; i < FIN * FH; i += 256)
    Wl[i >> 6][i & 63] = W[i];
  __syncthreads();

  int wave = threadIdx.x >> 6;
  int lane = threadIdx.x & 63;
  float asc = avs[lane];
  float adc = avd[lane];
  float4* xb = xbuf[wave];
  int nw = gridDim.x * 4;
  int ngroups = n >> 3;                      // n = 50000 = 8*6250
  for (int g = blockIdx.x * 4 + wave; g < ngroups; g += nw) {
    int r0 = g << 3;
    const float4* xg = reinterpret_cast<const float4*>(x + (size_t)r0 * FIN);
    for (int f = lane; f < 8 * K4; f += 64) xb[f] = xg[f];
    float acc[8];
#pragma unroll
    for (int r = 0; r < 8; ++r) acc[r] = 0.f;
#pragma unroll 2
    for (int k4 = 0; k4 < K4; ++k4) {
      int k = k4 * 4;
      float w0 = Wl[k + 0][lane];
      float w1 = Wl[k + 1][lane];
      float w2 = Wl[k + 2][lane];
      float w3 = Wl[k + 3][lane];
#pragma unroll
      for (int r = 0; r < 8; ++r) {
        float4 xv = xb[r * K4 + k4];
        acc[r] += xv.x * w0 + xv.y * w1 + xv.z * w2 + xv.w * w3;
      }
    }
#pragma unroll
    for (int r = 0; r < 8; ++r) {
      h[(size_t)(r0 + r) * FH + lane] = acc[r];
      float s = acc[r] * asc, d = acc[r] * adc;
#pragma unroll
      for (int off = 32; off; off >>= 1) {
        s += __shfl_xor(s, off);
        d += __shfl_xor(d, off);
      }
      if (lane == 0) { as[r0 + r] = s; ad[r0 + r] = d; }
    }
  }
}

// ---------------- per-dst softmax aggregation (gather) ----------------
// (unchanged from R8 — 4-way edge-parallel float4 gather)

__global__ void agg_kernel(const int* __restrict__ rowptr,
                           const int* __restrict__ eidx,
                           const float* __restrict__ h,
                           const float* __restrict__ as,
                           const float* __restrict__ ad,
                           const float* __restrict__ b,
                           float* __restrict__ out, int n, int doRelu) {
  int wave = (blockIdx.x * blockDim.x + threadIdx.x) >> 6;
  int lane = threadIdx.x & 63;
  int nwaves = (gridDim.x * blockDim.x) >> 6;
  int eq = lane >> 4;                         // edge slot 0..3
  int fq = lane & 15;                         // feature quad 0..15
  const float4* h4 = reinterpret_cast<const float4*>(h);
  float4 bc = reinterpret_cast<const float4*>(b)[fq];
  for (int dst = wave; dst < n; dst += nwaves) {
    int lo = rowptr[dst], hi = rowptr[dst + 1];
    float adv = ad[dst];
    // pass 1: max logit, 64-edge-parallel
    float m = -1e30f;
    for (int j = lo + lane; j < hi; j += 64) {
      float t = as[eidx[j]] + adv;
      t = (t > 0.f) ? t : NEG_SLOPE * t;
      m = fmaxf(m, t);
    }
#pragma unroll
    for (int off = 32; off; off >>= 1) m = fmaxf(m, __shfl_xor(m, off));
    // pass 2: 4 edges concurrently, float4 gathers
    float4 acc = {0.f, 0.f, 0.f, 0.f};
    float den = 0.f;
    for (int j = lo + eq; j < hi; j += 4) {
      int s = eidx[j];                        // group-uniform broadcast load
      float t = as[s] + adv;
      t = (t > 0.f) ? t : NEG_SLOPE * t;
      float w = __expf(t - m);
      den += w;
      float4 hv = h4[(size_t)s * 16 + fq];    // 16-lane x 16B = 256B gather
      acc.x += w * hv.x;
      acc.y += w * hv.y;
      acc.z += w * hv.z;
      acc.w += w * hv.w;
    }
    // combine the 4 edge groups (lanes {fq, fq+16, fq+32, fq+48})
#pragma unroll
    for (int off = 16; off < 64; off <<= 1) {
      acc.x += __shfl_xor(acc.x, off);
      acc.y += __shfl_xor(acc.y, off);
      acc.z += __shfl_xor(acc.z, off);
      acc.w += __shfl_xor(acc.w, off);
      den   += __shfl_xor(den, off);
    }
    if (eq == 0) {
      float inv = 1.f / (den + EPS);
      float4 o;
      o.x = acc.x * inv + bc.x;
      o.y = acc.y * inv + bc.y;
      o.z = acc.z * inv + bc.z;
      o.w = acc.w * inv + bc.w;
      if (doRelu) {
        o.x = fmaxf(o.x, 0.f); o.y = fmaxf(o.y, 0.f);
        o.z = fmaxf(o.z, 0.f); o.w = fmaxf(o.w, 0.f);
      }
      reinterpret_cast<float4*>(out)[(size_t)dst * 16 + fq] = o;
    }
  }
}

// ---------------- mean-pool per graph + final linear ----------------
// R13 v2: 256 threads (4 waves) per graph. lane=(rs=row-slot, fq=feature-quad)
// -> 16 rows in flight, float4 loads. Combine: shfl_xor over rs bits (16,32),
// LDS across waves, -> pooled[64]; wave 0 does the 10-class linear.

__global__ void pool_kernel(const int* __restrict__ batch,
                            const float* __restrict__ h,
                            const float* __restrict__ Wlin,
                            const float* __restrict__ blin,
                            float* __restrict__ outp, int n, int ncls) {
  int g = blockIdx.x;
  __shared__ int shb[2];
  __shared__ float4 ps[4][16];
  __shared__ float pooled[64];
  int t = threadIdx.x;                       // 0..255
  if (t == 0) {
    int lo = 0, hi = n;
    while (lo < hi) { int mid = (lo + hi) >> 1; if (batch[mid] < g) lo = mid + 1; else hi = mid; }
    shb[0] = lo;
    hi = n;
    while (lo < hi) { int mid = (lo + hi) >> 1; if (batch[mid] <= g) lo = mid + 1; else hi = mid; }
    shb[1] = lo;
  }
  __syncthreads();
  int lo = shb[0], hi = shb[1];
  int lane = t & 63, w = t >> 6;
  int rs = lane >> 4, fq = lane & 15;
  const float4* h4 = reinterpret_cast<const float4*>(h);
  float4 acc = {0.f, 0.f, 0.f, 0.f};
  for (int i = lo + (w << 2) + rs; i < hi; i += 16) {
    float4 v = h4[(size_t)i * 16 + fq];      // 16 lanes x 16B = 256B/row
    acc.x += v.x; acc.y += v.y; acc.z += v.z; acc.w += v.w;
  }
  // sum across row-slots rs (lane bits 4..5)
#pragma unroll
  for (int off = 16; off < 64; off <<= 1) {
    acc.x += __shfl_xor(acc.x, off);
    acc.y += __shfl_xor(acc.y, off);
    acc.z += __shfl_xor(acc.z, off);
    acc.w += __shfl_xor(acc.w, off);
  }
  if (lane < 16) ps[w][lane] = acc;
  __syncthreads();
  if (t < 16) {
    float4 s;
    s.x = ps[0][t].x + ps[1][t].x + ps[2][t].x + ps[3][t].x;
    s.y = ps[0][t].y + ps[1][t].y + ps[2][t].y + ps[3][t].y;
    s.z = ps[0][t].z + ps[1][t].z + ps[2][t].z + ps[3][t].z;
    s.w = ps[0][t].w + ps[1][t].w + ps[2][t].w + ps[3][t].w;
    float inv = 1.f / fmaxf((float)(hi - lo), 1.f);
    pooled[t * 4 + 0] = s.x * inv;
    pooled[t * 4 + 1] = s.y * inv;
    pooled[t * 4 + 2] = s.z * inv;
    pooled[t * 4 + 3] = s.w * inv;
  }
  __syncthreads();
  if (t < 64) {                              // wave 0 only
    float pl = pooled[t];
    for (int k = 0; k < ncls; ++k) {
      float v = pl * Wlin[t * ncls + k];
#pragma unroll
      for (int off = 32; off; off >>= 1) v += __shfl_xor(v, off);
      if (t == 0) outp[g * ncls + k] = v + blin[k];
    }
  }
}

// ---------------- launch ----------------

extern "C" void kernel_launch(void* const* d_in, const int* in_sizes, int n_in,
                              void* d_out, int out_size, void* d_ws, size_t ws_size,
                              hipStream_t stream) {
  const float* x    = (const float*)d_in[0];
  const int*   ei   = (const int*)d_in[1];
  const int*   batch= (const int*)d_in[2];
  const float* W1   = (const float*)d_in[3];
  const float* as1  = (const float*)d_in[4];
  const float* ad1  = (const float*)d_in[5];
  const float* b1   = (const float*)d_in[6];
  const float* W2   = (const float*)d_in[7];
  const float* as2  = (const float*)d_in[8];
  const float* ad2  = (const float*)d_in[9];
  const float* b2   = (const float*)d_in[10];
  const float* Wlin = (const float*)d_in[11];
  const float* blin = (const float*)d_in[12];
  float* outp = (float*)d_out;

  const int N  = in_sizes[2];        // 50000
  const int E  = in_sizes[1] / 2;    // 800000
  const int ET = E + N;              // + self loops
  const int NCLS = 10;
  const int NG = out_size / NCLS;    // 512

  char* p = (char*)d_ws;
  auto alloc = [&](size_t bytes) {
    char* r = p;
    p += (bytes + 255) & ~(size_t)255;
    return r;
  };
  float* hA      = (float*)alloc((size_t)N * FH * 4);
  float* hB      = (float*)alloc((size_t)N * FH * 4);
  float* asb     = (float*)alloc((size_t)N * 4);
  float* adb     = (float*)alloc((size_t)N * 4);
  int*   deg     = (int*)alloc((size_t)N * 4);
  int*   rowptr  = (int*)alloc((size_t)(N + 1) * 4);
  int*   rank    = (int*)alloc((size_t)ET * 4);
  int*   eidx    = (int*)alloc((size_t)ET * 4);
  int*   partial = (int*)alloc(64 * 4);
  (void)ws_size; (void)n_in;

  const int TB = 256;
  const int nb = (N + 1023) / 1024;  // 49 scan blocks (<=64 required)

  // CSR by dst (atomic-free scatter via rank trick)
  hipMemsetAsync(deg, 0, (size_t)N * 4, stream);
  hist_kernel<<<(ET + TB - 1) / TB, TB, 0, stream>>>(ei, deg, rank, E, N);
  scan_local_kernel<<<nb, 1024, 0, stream>>>(deg, rowptr, partial, N);
  scan_partial_kernel<<<1, 64, 0, stream>>>(partial, nb);
  scan_add_kernel<<<nb, 1024, 0, stream>>>(rowptr, partial, N, nb);
  scatter_kernel<<<(ET + TB - 1) / TB, TB, 0, stream>>>(ei, rowptr, rank, eidx, E, N);

  int aggBlocks = (N + 3) / 4;       // 4 waves/block, 1 wave/dst
  int gemmBlocks = (N / 8 + 3) / 4;  // 1563

  // layer 1
  gemm_alpha_kernel<128><<<gemmBlocks, TB, 0, stream>>>(x, W1, as1, ad1, hA, asb, adb, N);
  agg_kernel<<<aggBlocks, TB, 0, stream>>>(rowptr, eidx, hA, asb, adb, b1, hB, N, 1);

  // layer 2
  gemm_alpha_kernel<64><<<gemmBlocks, TB, 0, stream>>>(hB, W2, as2, ad2, hA, asb, adb, N);
  agg_kernel<<<aggBlocks, TB, 0, stream>>>(rowptr, eidx, hA, asb, adb, b2, hB, N, 0);

  // mean pool per graph + linear
  pool_kernel<<<NG, 256, 0, stream>>>(batch, hB, Wlin, blin, outp, N, NCLS);
}